// Round 9
// baseline (403.131 us; speedup 1.0000x reference)
//
#include <hip/hip_runtime.h>

// x[32,64,224,224] f32 -> BN(affine)+ReLU -> 1x1 conv(64->32) -> avgpool 2x2 s2
//   == relu-affine(0.25 folded) -> pool -> 32x64 matvec (conv commutes w/ pool).
// Memory-bound stream: 411MB read + 51MB write ~= 73.5us at 6.3 TB/s copy rate.
// Scoreboard: R1 104.8 | R6 94.3 | R7 87.4 | R8 reg-dbuf-via-lambda-ptr 300.6
//   (rule #20: pointer param defeated SROA -> buffers in scratch, VGPR=64).
// R9: same pipeline, buffers by NAME via token-pasting macros (no pointers,
//   all indices compile-time). CHK=4: ~85 VGPR -> lb(256,5), 20 waves/CU,
//   8 loads in flight per wave during every compute phase.

#define EPS_BN 1e-5f

typedef float v2f __attribute__((ext_vector_type(2)));

constexpr int N_   = 32;
constexpr int CIN  = 64;
constexpr int COUT = 32;
constexpr int H_   = 224;
constexpr int W_   = 224;
constexpr int H2   = 112;
constexpr int W2   = 112;
constexpr int PIX  = N_ * H2 * W2;       // 401408 pooled pixels, PIX%256==0
constexpr int BLK  = 256;
constexpr int CHK  = 4;                  // channels per pipeline chunk

// d_ws layout (floats): [0..63]=scale, [64..127]=bias, [128..2175]=wT[c][o]
__global__ void prep_kernel(const float* __restrict__ conv_w,
                            const float* __restrict__ gamma,
                            const float* __restrict__ beta,
                            const float* __restrict__ rmean,
                            const float* __restrict__ rvar,
                            float* __restrict__ ws) {
    int j = blockIdx.x * blockDim.x + threadIdx.x;   // 0..2047
    if (j < CIN * COUT) {
        int c = j >> 5, o = j & 31;                  // wT[c][o] = conv_w[o][c]
        ws[2 * CIN + j] = conv_w[o * CIN + c];       // contiguous per-c -> s_load_dwordx8
    }
    if (j < CIN) {
        float s = gamma[j] * rsqrtf(rvar[j] + EPS_BN);
        float b = beta[j] - rmean[j] * s;
        ws[j]       = 0.25f * s;   // fold 2x2-mean into BN affine
        ws[CIN + j] = 0.25f * b;
    }
}

__global__ __launch_bounds__(BLK, 5) void fused_kernel(const float* __restrict__ x,
                                                       const float* __restrict__ ws,
                                                       float* __restrict__ out) {
    const float* __restrict__ sc = ws;            // [64]
    const float* __restrict__ bi = ws + CIN;      // [64]
    const float* __restrict__ wT = ws + 2 * CIN;  // [64][32]

    int i = blockIdx.x * BLK + threadIdx.x;       // pooled pixel id
    int n  = i / (H2 * W2);
    int r  = i - n * (H2 * W2);
    int h2 = r / W2;
    int w2 = r - h2 * W2;

    // float index of the 2x2 window base (channel 0); fits uint32 (102.8M)
    uint32_t base = ((uint32_t)(n * CIN) * H_ + (uint32_t)(2 * h2)) * W_ + 2 * w2;

    float acc[COUT];
#pragma unroll
    for (int o = 0; o < COUT; ++o) acc[o] = 0.0f;

    // Two named register buffers; ONLY compile-time indices, never a pointer.
    v2f bufA[2 * CHK], bufB[2 * CHK];

#define LOADQ(BUF, c0)                                                         \
    _Pragma("unroll")                                                          \
    for (int c = 0; c < CHK; ++c) {                                            \
        uint32_t off = base + (uint32_t)((c0) + c) * (H_ * W_);                \
        BUF[2 * c] = __builtin_nontemporal_load(                               \
            reinterpret_cast<const v2f*>(x + off));                            \
        BUF[2 * c + 1] = __builtin_nontemporal_load(                           \
            reinterpret_cast<const v2f*>(x + off + W_));                       \
    }

#define COMPQ(BUF, c0)                                                         \
    _Pragma("unroll")                                                          \
    for (int c = 0; c < CHK; ++c) {                                            \
        float s = sc[(c0) + c];                                                \
        float b = bi[(c0) + c];                                                \
        v2f r0 = BUF[2 * c], r1 = BUF[2 * c + 1];                              \
        float y = fmaxf(fmaf(r0.x, s, b), 0.0f)                                \
                + fmaxf(fmaf(r0.y, s, b), 0.0f)                                \
                + fmaxf(fmaf(r1.x, s, b), 0.0f)                                \
                + fmaxf(fmaf(r1.y, s, b), 0.0f);                               \
        _Pragma("unroll")                                                      \
        for (int o = 0; o < COUT; ++o)                                         \
            acc[o] = fmaf(wT[((c0) + c) * COUT + o], y, acc[o]);               \
    }

    LOADQ(bufA, 0)
#pragma unroll
    for (int q = 0; q < CIN / (2 * CHK); ++q) {   // q=0..7, fully unrolled
        const int c0 = q * 2 * CHK;
        LOADQ(bufB, c0 + CHK)                     // prefetch next chunk
        __builtin_amdgcn_sched_barrier(0);        // loads stay above compute
        COMPQ(bufA, c0)
        if (c0 + 2 * CHK < CIN) { LOADQ(bufA, c0 + 2 * CHK) }
        __builtin_amdgcn_sched_barrier(0);
        COMPQ(bufB, c0 + CHK)
    }
#undef LOADQ
#undef COMPQ

    // out[((n*COUT + o)*H2 + h2)*W2 + w2]; never re-read -> nontemporal
    float* __restrict__ po = out + ((size_t)n * COUT * H2 + (size_t)h2) * W2 + (size_t)w2;
#pragma unroll
    for (int o = 0; o < COUT; ++o)
        __builtin_nontemporal_store(acc[o], po + (size_t)o * (H2 * W2));
}

extern "C" void kernel_launch(void* const* d_in, const int* in_sizes, int n_in,
                              void* d_out, int out_size, void* d_ws, size_t ws_size,
                              hipStream_t stream) {
    const float* x      = (const float*)d_in[0];
    const float* conv_w = (const float*)d_in[1];
    const float* gamma  = (const float*)d_in[2];
    const float* beta   = (const float*)d_in[3];
    const float* rmean  = (const float*)d_in[4];
    const float* rvar   = (const float*)d_in[5];
    float* out = (float*)d_out;
    float* ws  = (float*)d_ws;

    prep_kernel<<<(CIN * COUT + BLK - 1) / BLK, BLK, 0, stream>>>(
        conv_w, gamma, beta, rmean, rvar, ws);
    fused_kernel<<<PIX / BLK, BLK, 0, stream>>>(x, ws, out);
}

// Round 10
// 85.025 us; speedup vs baseline: 4.7413x; 4.7413x over previous
//
#include <hip/hip_runtime.h>

// x[32,64,224,224] f32 -> BN(affine)+ReLU -> 1x1 conv(64->32) -> avgpool 2x2 s2
//   == relu-affine(0.25 folded) -> pool -> 32x64 matvec (conv commutes w/ pool).
// Memory-bound stream: 411MB read + 51MB write ~= 73.5us at 6.3 TB/s copy rate.
// Scoreboard: R1 104.8 | R6 unroll4 94.3 | R7 unroll8+lb(256,5) 87.4 |
//   R8/R9 explicit reg-dbuf -> scratch (VGPR 64/48, WRITE_SIZE 12x) 300/403.
// R10: abandon explicit dbuf; deepen the IMPLICIT pipeline the compiler
//   already builds for a plain unrolled loop (loads hoisted above consumes):
//   unroll 16 (32 loads ~8KB in flight/wave) + lb(256,4) (VGPR cap 128,
//   16 waves/CU). Calibrates the loads-in-flight x occupancy curve's far end.

#define EPS_BN 1e-5f

typedef float v2f __attribute__((ext_vector_type(2)));

constexpr int N_   = 32;
constexpr int CIN  = 64;
constexpr int COUT = 32;
constexpr int H_   = 224;
constexpr int W_   = 224;
constexpr int H2   = 112;
constexpr int W2   = 112;
constexpr int PIX  = N_ * H2 * W2;       // 401408 pooled pixels, PIX%256==0
constexpr int BLK  = 256;

// d_ws layout (floats): [0..63]=scale, [64..127]=bias, [128..2175]=wT[c][o]
__global__ void prep_kernel(const float* __restrict__ conv_w,
                            const float* __restrict__ gamma,
                            const float* __restrict__ beta,
                            const float* __restrict__ rmean,
                            const float* __restrict__ rvar,
                            float* __restrict__ ws) {
    int j = blockIdx.x * blockDim.x + threadIdx.x;   // 0..2047
    if (j < CIN * COUT) {
        int c = j >> 5, o = j & 31;                  // wT[c][o] = conv_w[o][c]
        ws[2 * CIN + j] = conv_w[o * CIN + c];       // contiguous per-c -> s_load batches
    }
    if (j < CIN) {
        float s = gamma[j] * rsqrtf(rvar[j] + EPS_BN);
        float b = beta[j] - rmean[j] * s;
        ws[j]       = 0.25f * s;   // fold 2x2-mean into BN affine
        ws[CIN + j] = 0.25f * b;
    }
}

__global__ __launch_bounds__(BLK, 4) void fused_kernel(const float* __restrict__ x,
                                                       const float* __restrict__ ws,
                                                       float* __restrict__ out) {
    const float* __restrict__ sc = ws;            // [64]
    const float* __restrict__ bi = ws + CIN;      // [64]
    const float* __restrict__ wT = ws + 2 * CIN;  // [64][32]

    int i = blockIdx.x * BLK + threadIdx.x;       // pooled pixel id
    int n  = i / (H2 * W2);
    int r  = i - n * (H2 * W2);
    int h2 = r / W2;
    int w2 = r - h2 * W2;

    // base of the 2x2 window for channel 0
    const float* __restrict__ px =
        x + ((size_t)n * CIN * H_ + (size_t)(2 * h2)) * W_ + (size_t)(2 * w2);

    float acc[COUT];
#pragma unroll
    for (int o = 0; o < COUT; ++o) acc[o] = 0.0f;

#pragma unroll 16  // 32 loads (~8KB/wave) hoisted in flight; VGPR capped by lb(256,4)
    for (int c = 0; c < CIN; ++c) {
        const float* p = px + (size_t)c * (H_ * W_);
        v2f r0 = __builtin_nontemporal_load(reinterpret_cast<const v2f*>(p));
        v2f r1 = __builtin_nontemporal_load(reinterpret_cast<const v2f*>(p + W_));
        float s = sc[c];   // uniform address -> s_load, broadcast
        float b = bi[c];
        float y = fmaxf(fmaf(r0.x, s, b), 0.0f)
                + fmaxf(fmaf(r0.y, s, b), 0.0f)
                + fmaxf(fmaf(r1.x, s, b), 0.0f)
                + fmaxf(fmaf(r1.y, s, b), 0.0f);
#pragma unroll
        for (int o = 0; o < COUT; ++o)
            acc[o] = fmaf(wT[c * COUT + o], y, acc[o]);  // wT uniform -> SGPR operand
    }

    // out[((n*COUT + o)*H2 + h2)*W2 + w2]; never re-read -> nontemporal
    float* __restrict__ po = out + ((size_t)n * COUT * H2 + (size_t)h2) * W2 + (size_t)w2;
#pragma unroll
    for (int o = 0; o < COUT; ++o)
        __builtin_nontemporal_store(acc[o], po + (size_t)o * (H2 * W2));
}

extern "C" void kernel_launch(void* const* d_in, const int* in_sizes, int n_in,
                              void* d_out, int out_size, void* d_ws, size_t ws_size,
                              hipStream_t stream) {
    const float* x      = (const float*)d_in[0];
    const float* conv_w = (const float*)d_in[1];
    const float* gamma  = (const float*)d_in[2];
    const float* beta   = (const float*)d_in[3];
    const float* rmean  = (const float*)d_in[4];
    const float* rvar   = (const float*)d_in[5];
    float* out = (float*)d_out;
    float* ws  = (float*)d_ws;

    prep_kernel<<<(CIN * COUT + BLK - 1) / BLK, BLK, 0, stream>>>(
        conv_w, gamma, beta, rmean, rvar, ws);
    fused_kernel<<<PIX / BLK, BLK, 0, stream>>>(x, ws, out);
}

// Round 11
// 82.637 us; speedup vs baseline: 4.8783x; 1.0289x over previous
//
#include <hip/hip_runtime.h>

// x[32,64,224,224] f32 -> BN(affine)+ReLU -> 1x1 conv(64->32) -> avgpool 2x2 s2
//   == relu-affine(0.25 folded) -> pool -> 32x64 matvec (conv commutes w/ pool).
// Memory-bound stream: 411MB read + 51MB write ~= 73.5us at 6.3 TB/s copy rate.
// Scoreboard: R1 104.8 | R6 unroll4 94.3 | R7 unroll8/lb5 87.4 | R10 unroll16/lb4
//   85.0 (5.45 TB/s) | R8/R9 explicit reg-dbuf -> scratch, abandoned.
// R11: last point on the unroll/occupancy curve -- unroll 32 (64 loads ~32KB
//   burst/wave) + lb(256,3) (cap 170 VGPR, 12 waves/CU). If this doesn't beat
//   85.0 the R10 structure is the pattern's practical ceiling (~87% of copy).

#define EPS_BN 1e-5f

typedef float v2f __attribute__((ext_vector_type(2)));

constexpr int N_   = 32;
constexpr int CIN  = 64;
constexpr int COUT = 32;
constexpr int H_   = 224;
constexpr int W_   = 224;
constexpr int H2   = 112;
constexpr int W2   = 112;
constexpr int PIX  = N_ * H2 * W2;       // 401408 pooled pixels, PIX%256==0
constexpr int BLK  = 256;

// d_ws layout (floats): [0..63]=scale, [64..127]=bias, [128..2175]=wT[c][o]
__global__ void prep_kernel(const float* __restrict__ conv_w,
                            const float* __restrict__ gamma,
                            const float* __restrict__ beta,
                            const float* __restrict__ rmean,
                            const float* __restrict__ rvar,
                            float* __restrict__ ws) {
    int j = blockIdx.x * blockDim.x + threadIdx.x;   // 0..2047
    if (j < CIN * COUT) {
        int c = j >> 5, o = j & 31;                  // wT[c][o] = conv_w[o][c]
        ws[2 * CIN + j] = conv_w[o * CIN + c];       // contiguous per-c -> s_load batches
    }
    if (j < CIN) {
        float s = gamma[j] * rsqrtf(rvar[j] + EPS_BN);
        float b = beta[j] - rmean[j] * s;
        ws[j]       = 0.25f * s;   // fold 2x2-mean into BN affine
        ws[CIN + j] = 0.25f * b;
    }
}

__global__ __launch_bounds__(BLK, 3) void fused_kernel(const float* __restrict__ x,
                                                       const float* __restrict__ ws,
                                                       float* __restrict__ out) {
    const float* __restrict__ sc = ws;            // [64]
    const float* __restrict__ bi = ws + CIN;      // [64]
    const float* __restrict__ wT = ws + 2 * CIN;  // [64][32]

    int i = blockIdx.x * BLK + threadIdx.x;       // pooled pixel id
    int n  = i / (H2 * W2);
    int r  = i - n * (H2 * W2);
    int h2 = r / W2;
    int w2 = r - h2 * W2;

    // base of the 2x2 window for channel 0
    const float* __restrict__ px =
        x + ((size_t)n * CIN * H_ + (size_t)(2 * h2)) * W_ + (size_t)(2 * w2);

    float acc[COUT];
#pragma unroll
    for (int o = 0; o < COUT; ++o) acc[o] = 0.0f;

#pragma unroll 32  // 64 loads (~32KB/wave) hoisted per burst; VGPR cap 170 (lb 256,3)
    for (int c = 0; c < CIN; ++c) {
        const float* p = px + (size_t)c * (H_ * W_);
        v2f r0 = __builtin_nontemporal_load(reinterpret_cast<const v2f*>(p));
        v2f r1 = __builtin_nontemporal_load(reinterpret_cast<const v2f*>(p + W_));
        float s = sc[c];   // uniform address -> s_load, broadcast
        float b = bi[c];
        float y = fmaxf(fmaf(r0.x, s, b), 0.0f)
                + fmaxf(fmaf(r0.y, s, b), 0.0f)
                + fmaxf(fmaf(r1.x, s, b), 0.0f)
                + fmaxf(fmaf(r1.y, s, b), 0.0f);
#pragma unroll
        for (int o = 0; o < COUT; ++o)
            acc[o] = fmaf(wT[c * COUT + o], y, acc[o]);  // wT uniform -> SGPR operand
    }

    // out[((n*COUT + o)*H2 + h2)*W2 + w2]; never re-read -> nontemporal
    float* __restrict__ po = out + ((size_t)n * COUT * H2 + (size_t)h2) * W2 + (size_t)w2;
#pragma unroll
    for (int o = 0; o < COUT; ++o)
        __builtin_nontemporal_store(acc[o], po + (size_t)o * (H2 * W2));
}

extern "C" void kernel_launch(void* const* d_in, const int* in_sizes, int n_in,
                              void* d_out, int out_size, void* d_ws, size_t ws_size,
                              hipStream_t stream) {
    const float* x      = (const float*)d_in[0];
    const float* conv_w = (const float*)d_in[1];
    const float* gamma  = (const float*)d_in[2];
    const float* beta   = (const float*)d_in[3];
    const float* rmean  = (const float*)d_in[4];
    const float* rvar   = (const float*)d_in[5];
    float* out = (float*)d_out;
    float* ws  = (float*)d_ws;

    prep_kernel<<<(CIN * COUT + BLK - 1) / BLK, BLK, 0, stream>>>(
        conv_w, gamma, beta, rmean, rvar, ws);
    fused_kernel<<<PIX / BLK, BLK, 0, stream>>>(x, ws, out);
}